// Round 1
// baseline (1045.992 us; speedup 1.0000x reference)
//
#include <hip/hip_runtime.h>
#include <hip/hip_bf16.h>
#include <math.h>

#define B_SZ 4096
#define NT 26
#define V_SZ 100000
#define D_SZ 64

// ---------------- GEMM: C[m,n] = act( sum_k A[m,k] * W[n,k] + bias[n] ) ----------------
// A: (M,K) row-major with leading dim lda. W: (N,K) row-major. C: leading dim ldc.
#define BM 64
#define BN 64
#define BKK 16

template<bool RELU>
__global__ __launch_bounds__(256) void gemm_nt(
    const float* __restrict__ A, int lda,
    const float* __restrict__ W,
    const float* __restrict__ bias,
    float* __restrict__ C, int ldc,
    int M, int N, int K)
{
    __shared__ float As[BKK][BM + 4];
    __shared__ float Ws[BKK][BN + 4];

    const int bm = blockIdx.x * BM;
    const int bn = blockIdx.y * BN;
    const int tid = threadIdx.x;

    // loader mapping: 256 threads cover a 64(row) x 16(k) tile, 4 scalars each
    const int lr = tid >> 2;          // 0..63 row within tile
    const int lk = (tid & 3) * 4;     // 0,4,8,12 k offset

    // compute mapping: 16x16 threads, each 4x4 outputs
    const int tm0 = (tid >> 4) * 4;
    const int tn0 = (tid & 15) * 4;

    float acc[4][4] = {};

    for (int k0 = 0; k0 < K; k0 += BKK) {
#pragma unroll
        for (int i = 0; i < 4; ++i) {
            int k = k0 + lk + i;
            As[lk + i][lr] = (k < K) ? A[(size_t)(bm + lr) * lda + k] : 0.f;
            Ws[lk + i][lr] = (k < K) ? W[(size_t)(bn + lr) * K + k] : 0.f;
        }
        __syncthreads();

        const int kmax = (K - k0 < BKK) ? (K - k0) : BKK;
        for (int kk = 0; kk < kmax; ++kk) {
            float4 av = *(const float4*)&As[kk][tm0];
            float4 bv = *(const float4*)&Ws[kk][tn0];
            float a0[4] = {av.x, av.y, av.z, av.w};
            float b0[4] = {bv.x, bv.y, bv.z, bv.w};
#pragma unroll
            for (int i = 0; i < 4; ++i)
#pragma unroll
                for (int j = 0; j < 4; ++j)
                    acc[i][j] += a0[i] * b0[j];
        }
        __syncthreads();
    }

#pragma unroll
    for (int i = 0; i < 4; ++i) {
        int m = bm + tm0 + i;
#pragma unroll
        for (int j = 0; j < 4; ++j) {
            int n = bn + tn0 + j;
            float v = acc[i][j] + bias[n];
            if (RELU) v = fmaxf(v, 0.f);
            C[(size_t)m * ldc + n] = v;
        }
    }
}

// ---------------- Embedding gather-sum: one wave per (table, sample) ----------------
// Writes directly into T layout: T[b, 1+t, :]
__global__ __launch_bounds__(256) void embed_sum(
    const int* __restrict__ idx,          // (NT, B, 4) int32
    const float* __restrict__ tables,     // (NT, V, 64)
    float* __restrict__ T)                // (B, 27, 64)
{
    int gw = (blockIdx.x * blockDim.x + threadIdx.x) >> 6;
    int lane = threadIdx.x & 63;
    if (gw >= NT * B_SZ) return;
    int t = gw >> 12;           // / 4096
    int b = gw & (B_SZ - 1);

    const int* ip = idx + ((size_t)t * B_SZ + b) * 4;
    const float* tbl = tables + (size_t)t * V_SZ * D_SZ;

    float acc = 0.f;
#pragma unroll
    for (int l = 0; l < 4; ++l) {
        int r = ip[l];
        acc += tbl[(size_t)r * D_SZ + lane];
    }
    T[((size_t)b * 27 + 1 + t) * D_SZ + lane] = acc;
}

// ---------------- Interaction: per-sample Z = T T^T strict lower triangle ----------------
__global__ __launch_bounds__(256) void interact(
    const float* __restrict__ T,   // (B, 27, 64)
    float* __restrict__ R)         // (B, 415)
{
    __shared__ float Ts[27][65];
    const int b = blockIdx.x;
    const int tid = threadIdx.x;
    const float* Tb = T + (size_t)b * 27 * 64;

    for (int i = tid; i < 27 * 64; i += 256)
        Ts[i >> 6][i & 63] = Tb[i];
    __syncthreads();

    float* Rb = R + (size_t)b * 415;
    if (tid < 64) Rb[tid] = Ts[0][tid];

    for (int p = tid; p < 351; p += 256) {
        // p = i*(i-1)/2 + j, 0 <= j < i  (np.tril_indices(27,-1) row-major order)
        int i = (int)((1.0f + sqrtf(1.0f + 8.0f * (float)p)) * 0.5f);
        while (i * (i - 1) / 2 > p) --i;
        while ((i + 1) * i / 2 <= p) ++i;
        int j = p - i * (i - 1) / 2;

        float acc = 0.f;
#pragma unroll 8
        for (int k = 0; k < 64; ++k)
            acc += Ts[i][k] * Ts[j][k];
        Rb[64 + p] = acc;
    }
}

// ---------------- Final layer: dot(256) + bias + sigmoid, one wave per row ----------------
__global__ __launch_bounds__(256) void final_dot(
    const float* __restrict__ Z1,   // (B, 256)
    const float* __restrict__ w,    // (1, 256)
    const float* __restrict__ bias, // (1,)
    float* __restrict__ out)        // (B,)
{
    int wid = (blockIdx.x * blockDim.x + threadIdx.x) >> 6;
    int lane = threadIdx.x & 63;
    if (wid >= B_SZ) return;

    float acc = 0.f;
#pragma unroll
    for (int u = 0; u < 4; ++u) {
        int k = lane + 64 * u;
        acc += Z1[(size_t)wid * 256 + k] * w[k];
    }
#pragma unroll
    for (int off = 32; off > 0; off >>= 1)
        acc += __shfl_down(acc, off, 64);

    if (lane == 0) {
        float z = acc + bias[0];
        out[wid] = 1.f / (1.f + expf(-z));
    }
}

extern "C" void kernel_launch(void* const* d_in, const int* in_sizes, int n_in,
                              void* d_out, int out_size, void* d_ws, size_t ws_size,
                              hipStream_t stream) {
    const float* x    = (const float*)d_in[0];
    const int*   lS_i = (const int*)d_in[1];
    const float* emb  = (const float*)d_in[2];
    const float* bw0  = (const float*)d_in[3];
    const float* bb0  = (const float*)d_in[4];
    const float* bw1  = (const float*)d_in[5];
    const float* bb1  = (const float*)d_in[6];
    const float* bw2  = (const float*)d_in[7];
    const float* bb2  = (const float*)d_in[8];
    const float* tw0  = (const float*)d_in[9];
    const float* tb0  = (const float*)d_in[10];
    const float* tw1  = (const float*)d_in[11];
    const float* tb1  = (const float*)d_in[12];
    const float* tw2  = (const float*)d_in[13];
    const float* tb2  = (const float*)d_in[14];
    float* out = (float*)d_out;

    // workspace layout (floats)
    float* ws = (float*)d_ws;
    float* T  = ws;                              // 4096*27*64  = 7,077,888
    float* H0 = T  + (size_t)B_SZ * 27 * 64;     // 4096*512    = 2,097,152 (aliased with Z0)
    float* H1 = H0 + (size_t)B_SZ * 512;         // 4096*256    = 1,048,576 (aliased with Z1)
    float* R  = H1 + (size_t)B_SZ * 256;         // 4096*415    = 1,699,840
    float* Z0 = H0;
    float* Z1 = H1;

    // embedding gather (independent of bottom MLP)
    {
        int waves = NT * B_SZ;
        int blocks = (waves * 64 + 255) / 256;
        embed_sum<<<blocks, 256, 0, stream>>>(lS_i, emb, T);
    }

    // bottom MLP
    gemm_nt<true><<<dim3(B_SZ / BM, 512 / BN), 256, 0, stream>>>(x, 13, bw0, bb0, H0, 512, B_SZ, 512, 13);
    gemm_nt<true><<<dim3(B_SZ / BM, 256 / BN), 256, 0, stream>>>(H0, 512, bw1, bb1, H1, 256, B_SZ, 256, 512);
    // layer 2 writes h directly into T[b, 0, :]  (ldc = 27*64)
    gemm_nt<true><<<dim3(B_SZ / BM, 64 / BN), 256, 0, stream>>>(H1, 256, bw2, bb2, T, 27 * 64, B_SZ, 64, 256);

    // interaction -> R (4096 x 415)
    interact<<<B_SZ, 256, 0, stream>>>(T, R);

    // top MLP
    gemm_nt<true><<<dim3(B_SZ / BM, 512 / BN), 256, 0, stream>>>(R, 415, tw0, tb0, Z0, 512, B_SZ, 512, 415);
    gemm_nt<true><<<dim3(B_SZ / BM, 256 / BN), 256, 0, stream>>>(Z0, 512, tw1, tb1, Z1, 256, B_SZ, 256, 512);

    // final dot + sigmoid
    final_dot<<<B_SZ / 4, 256, 0, stream>>>(Z1, tw2, tb2, out);
}

// Round 2
// 809.776 us; speedup vs baseline: 1.2917x; 1.2917x over previous
//
#include <hip/hip_runtime.h>
#include <hip/hip_bf16.h>
#include <math.h>

#define B_SZ 4096
#define NT 26
#define V_SZ 100000
#define D_SZ 64

typedef short bf16x8 __attribute__((ext_vector_type(8)));
typedef float f32x4  __attribute__((ext_vector_type(4)));

__device__ inline void gl_lds16(const void* g, void* l) {
    __builtin_amdgcn_global_load_lds(
        (const __attribute__((address_space(1))) void*)g,
        (__attribute__((address_space(3))) void*)l,
        16, 0, 0);
}

// ---------------- bf16 MFMA GEMM: C[m,n] = act(sum_k A[m,k]*W[n,k] + bias[n]) ----------------
// A: (M,K) bf16 row-major lda. W: (N,K) bf16 row-major ldw. C bf16 ldc.
// K % 64 == 0, M % 64 == 0, N % 64 == 0. Block = 64x64 tile, 256 thr (4 waves, 32x32 each).
template<bool RELU>
__global__ __launch_bounds__(256) void gemm_bf16(
    const __hip_bfloat16* __restrict__ A, int lda,
    const __hip_bfloat16* __restrict__ W, int ldw,
    const float* __restrict__ bias,
    __hip_bfloat16* __restrict__ C, int ldc,
    int K)
{
    __shared__ __hip_bfloat16 As[64 * 64];   // row stride 64 elems (128 B)
    __shared__ __hip_bfloat16 Ws[64 * 64];

    const int tid  = threadIdx.x;
    const int lane = tid & 63;
    const int wv   = tid >> 6;
    const int bm = blockIdx.x * 64;
    const int bn = blockIdx.y * 64;
    const int wm = (wv & 1) * 32;
    const int wn = (wv >> 1) * 32;

    // staging: 512 16B segments per 8KB tile; thread covers seg tid and tid+256
    const int r0 = tid >> 3;             // rows 0..31
    const int q0 = (tid & 7) * 8;        // k offset in elems
    const int d0 = tid * 8;              // LDS elem offset of seg tid
    const int d1 = (tid + 256) * 8;

    f32x4 zero4 = {0.f, 0.f, 0.f, 0.f};
    f32x4 acc[2][2];
    acc[0][0] = zero4; acc[0][1] = zero4; acc[1][0] = zero4; acc[1][1] = zero4;

    const int rA = lane & 15;
    const int qk = (lane >> 4) * 8;

    for (int k0 = 0; k0 < K; k0 += 64) {
        gl_lds16(A + (size_t)(bm + r0) * lda + k0 + q0,      As + d0);
        gl_lds16(A + (size_t)(bm + 32 + r0) * lda + k0 + q0, As + d1);
        gl_lds16(W + (size_t)(bn + r0) * ldw + k0 + q0,      Ws + d0);
        gl_lds16(W + (size_t)(bn + 32 + r0) * ldw + k0 + q0, Ws + d1);
        __syncthreads();

#pragma unroll
        for (int kk = 0; kk < 2; ++kk) {
            bf16x8 a0 = *(const bf16x8*)(As + (wm + rA) * 64 + kk * 32 + qk);
            bf16x8 a1 = *(const bf16x8*)(As + (wm + 16 + rA) * 64 + kk * 32 + qk);
            bf16x8 b0 = *(const bf16x8*)(Ws + (wn + rA) * 64 + kk * 32 + qk);
            bf16x8 b1 = *(const bf16x8*)(Ws + (wn + 16 + rA) * 64 + kk * 32 + qk);
            acc[0][0] = __builtin_amdgcn_mfma_f32_16x16x32_bf16(a0, b0, acc[0][0], 0, 0, 0);
            acc[0][1] = __builtin_amdgcn_mfma_f32_16x16x32_bf16(a0, b1, acc[0][1], 0, 0, 0);
            acc[1][0] = __builtin_amdgcn_mfma_f32_16x16x32_bf16(a1, b0, acc[1][0], 0, 0, 0);
            acc[1][1] = __builtin_amdgcn_mfma_f32_16x16x32_bf16(a1, b1, acc[1][1], 0, 0, 0);
        }
        __syncthreads();
    }

    // epilogue: D[row=(lane>>4)*4+r][col=lane&15]
    const int col   = lane & 15;
    const int rbase = (lane >> 4) * 4;
#pragma unroll
    for (int i = 0; i < 2; ++i) {
#pragma unroll
        for (int j = 0; j < 2; ++j) {
            int n = bn + wn + j * 16 + col;
            float bs = bias[n];
#pragma unroll
            for (int r = 0; r < 4; ++r) {
                int m = bm + wm + i * 16 + rbase + r;
                float v = acc[i][j][r] + bs;
                if (RELU) v = fmaxf(v, 0.f);
                C[(size_t)m * ldc + n] = __float2bfloat16(v);
            }
        }
    }
}

// ---------------- weight conversion f32 -> bf16 (tw0 padded 415 -> 448 with zeros) ----------------
__global__ __launch_bounds__(256) void convert_weights(
    const float* __restrict__ bw1, const float* __restrict__ bw2,
    const float* __restrict__ tw0, const float* __restrict__ tw1,
    __hip_bfloat16* __restrict__ bw1c, __hip_bfloat16* __restrict__ bw2c,
    __hip_bfloat16* __restrict__ tw0c, __hip_bfloat16* __restrict__ tw1c)
{
    int i = blockIdx.x * 256 + threadIdx.x;
    if (i < 131072) {
        bw1c[i] = __float2bfloat16(bw1[i]);
    } else if (i < 147456) {
        int j = i - 131072;
        bw2c[j] = __float2bfloat16(bw2[j]);
    } else if (i < 376832) {
        int j = i - 147456;            // 512*448 = 229376
        int row = j / 448, cl = j - row * 448;
        tw0c[j] = (cl < 415) ? __float2bfloat16(tw0[row * 415 + cl]) : __float2bfloat16(0.f);
    } else if (i < 507904) {
        int j = i - 376832;
        tw1c[j] = __float2bfloat16(tw1[j]);
    }
}

// ---------------- first layer: (4096x13) @ (512x13)^T, thread per output ----------------
__global__ __launch_bounds__(256) void mlp0(
    const float* __restrict__ x, const float* __restrict__ w,
    const float* __restrict__ bias, __hip_bfloat16* __restrict__ H0)
{
    int g = blockIdx.x * 256 + threadIdx.x;   // < 4096*512
    int m = g >> 9, n = g & 511;
    const float* xr = x + m * 13;
    const float* wr = w + n * 13;
    float acc = bias[n];
#pragma unroll
    for (int k = 0; k < 13; ++k) acc += xr[k] * wr[k];
    H0[g] = __float2bfloat16(fmaxf(acc, 0.f));
}

// ---------------- embedding gather-sum: one wave per (table, sample) -> T bf16 ----------------
__global__ __launch_bounds__(256) void embed_sum(
    const int* __restrict__ idx,          // (NT, B, 4) int32
    const float* __restrict__ tables,     // (NT, V, 64) f32
    __hip_bfloat16* __restrict__ T)       // (B, 27, 64) bf16
{
    int gw = (blockIdx.x * blockDim.x + threadIdx.x) >> 6;
    int lane = threadIdx.x & 63;
    if (gw >= NT * B_SZ) return;
    int t = gw >> 12;
    int b = gw & (B_SZ - 1);

    const int* ip = idx + ((size_t)t * B_SZ + b) * 4;
    const float* tbl = tables + (size_t)t * V_SZ * D_SZ;

    float acc = 0.f;
#pragma unroll
    for (int l = 0; l < 4; ++l) {
        int r = ip[l];
        acc += tbl[(size_t)r * D_SZ + lane];
    }
    T[((size_t)b * 27 + 1 + t) * D_SZ + lane] = __float2bfloat16(acc);
}

// ---------------- interaction: R[b] = [h | tril(T T^T)] padded to 448 ----------------
__global__ __launch_bounds__(256) void interact(
    const __hip_bfloat16* __restrict__ T,   // (B, 27, 64)
    __hip_bfloat16* __restrict__ R)         // (B, 448)
{
    __shared__ float Ts[27][65];
    const int b = blockIdx.x;
    const int tid = threadIdx.x;
    const __hip_bfloat16* Tb = T + (size_t)b * 27 * 64;

    for (int i = tid; i < 27 * 64; i += 256)
        Ts[i >> 6][i & 63] = __bfloat162float(Tb[i]);
    __syncthreads();

    __hip_bfloat16* Rb = R + (size_t)b * 448;
    if (tid < 64) Rb[tid] = Tb[tid];                       // h passthrough (already bf16)
    if (tid >= 64 && tid < 97) Rb[415 + tid - 64] = __float2bfloat16(0.f);  // pad cols

    for (int p = tid; p < 351; p += 256) {
        int i = (int)((1.0f + sqrtf(1.0f + 8.0f * (float)p)) * 0.5f);
        while (i * (i - 1) / 2 > p) --i;
        while ((i + 1) * i / 2 <= p) ++i;
        int j = p - i * (i - 1) / 2;

        float acc = 0.f;
#pragma unroll 8
        for (int k = 0; k < 64; ++k)
            acc += Ts[i][k] * Ts[j][k];
        Rb[64 + p] = __float2bfloat16(acc);
    }
}

// ---------------- final layer: dot(256) + bias + sigmoid, one wave per row ----------------
__global__ __launch_bounds__(256) void final_dot(
    const __hip_bfloat16* __restrict__ Z1,  // (B, 256)
    const float* __restrict__ w,            // (256,)
    const float* __restrict__ bias,         // (1,)
    float* __restrict__ out)                // (B,)
{
    int wid = (blockIdx.x * blockDim.x + threadIdx.x) >> 6;
    int lane = threadIdx.x & 63;
    if (wid >= B_SZ) return;

    float acc = 0.f;
#pragma unroll
    for (int u = 0; u < 4; ++u) {
        int k = lane + 64 * u;
        acc += __bfloat162float(Z1[(size_t)wid * 256 + k]) * w[k];
    }
#pragma unroll
    for (int off = 32; off > 0; off >>= 1)
        acc += __shfl_down(acc, off, 64);

    if (lane == 0) {
        float z = acc + bias[0];
        out[wid] = 1.f / (1.f + expf(-z));
    }
}

extern "C" void kernel_launch(void* const* d_in, const int* in_sizes, int n_in,
                              void* d_out, int out_size, void* d_ws, size_t ws_size,
                              hipStream_t stream) {
    const float* x    = (const float*)d_in[0];
    const int*   lS_i = (const int*)d_in[1];
    const float* emb  = (const float*)d_in[2];
    const float* bw0  = (const float*)d_in[3];
    const float* bb0  = (const float*)d_in[4];
    const float* bw1  = (const float*)d_in[5];
    const float* bb1  = (const float*)d_in[6];
    const float* bw2  = (const float*)d_in[7];
    const float* bb2  = (const float*)d_in[8];
    const float* tw0  = (const float*)d_in[9];
    const float* tb0  = (const float*)d_in[10];
    const float* tw1  = (const float*)d_in[11];
    const float* tb1  = (const float*)d_in[12];
    const float* tw2  = (const float*)d_in[13];
    const float* tb2  = (const float*)d_in[14];
    float* out = (float*)d_out;

    // workspace layout (bf16 elements, all offsets 16B-aligned)
    __hip_bfloat16* ws = (__hip_bfloat16*)d_ws;
    __hip_bfloat16* T    = ws;                                   // 4096*27*64 = 7,077,888
    __hip_bfloat16* H0   = T    + (size_t)B_SZ * 27 * 64;        // 4096*512
    __hip_bfloat16* H1   = H0   + (size_t)B_SZ * 512;            // 4096*256
    __hip_bfloat16* R    = H1   + (size_t)B_SZ * 256;            // 4096*448
    __hip_bfloat16* bw1c = R    + (size_t)B_SZ * 448;            // 256*512
    __hip_bfloat16* bw2c = bw1c + 131072;                        // 64*256
    __hip_bfloat16* tw0c = bw2c + 16384;                         // 512*448
    __hip_bfloat16* tw1c = tw0c + 229376;                        // 256*512
    __hip_bfloat16* Z0 = H0;   // alias (H0 dead after layer 1)
    __hip_bfloat16* Z1 = H1;   // alias (H1 dead after layer 2)

    convert_weights<<<1984, 256, 0, stream>>>(bw1, bw2, tw0, tw1, bw1c, bw2c, tw0c, tw1c);

    mlp0<<<8192, 256, 0, stream>>>(x, bw0, bb0, H0);

    embed_sum<<<(NT * B_SZ * 64) / 256, 256, 0, stream>>>(lS_i, emb, T);

    // bottom MLP layers 1,2 (layer 2 writes h into T[b,0,:], ldc = 27*64)
    gemm_bf16<true><<<dim3(64, 4), 256, 0, stream>>>(H0, 512, bw1c, 512, bb1, H1, 256, 512);
    gemm_bf16<true><<<dim3(64, 1), 256, 0, stream>>>(H1, 256, bw2c, 256, bb2, T, 27 * 64, 256);

    interact<<<B_SZ, 256, 0, stream>>>(T, R);

    // top MLP
    gemm_bf16<true><<<dim3(64, 8), 256, 0, stream>>>(R, 448, tw0c, 448, tb0, Z0, 512, 448);
    gemm_bf16<true><<<dim3(64, 4), 256, 0, stream>>>(Z0, 512, tw1c, 512, tb1, Z1, 256, 512);

    final_dot<<<B_SZ / 4, 256, 0, stream>>>(Z1, tw2, tb2, out);
}